// Round 6
// baseline (344.884 us; speedup 1.0000x reference)
//
#include <hip/hip_runtime.h>
#include <hip/hip_bf16.h>

#define NN 2048

typedef __attribute__((ext_vector_type(4))) float f32x4;
typedef __attribute__((ext_vector_type(8))) short bf16x8;

__device__ __forceinline__ unsigned short f2bf(float f) {
  __hip_bfloat16 h = __float2bfloat16(f);
  return __builtin_bit_cast(unsigned short, h);
}
__device__ __forceinline__ unsigned int pk2(float a, float b) {
  return (unsigned int)f2bf(a) | ((unsigned int)f2bf(b) << 16);
}
__device__ __forceinline__ void gld_lds16(const void* g, void* l) {
  __builtin_amdgcn_global_load_lds(
      (const __attribute__((address_space(1))) unsigned int*)g,
      (__attribute__((address_space(3))) unsigned int*)l, 16, 0, 0);
}

// Merged transpose+cvt: f32 (R x C) -> bf16 (C x R) for X (batched), W1, W2.
__global__ void k_tr_all(const float* __restrict__ X, unsigned short* __restrict__ XT,
                         const float* __restrict__ W1, unsigned short* __restrict__ W1T,
                         const float* __restrict__ W2, unsigned short* __restrict__ W2T) {
  int bid = blockIdx.x;
  const float* src;
  unsigned short* dst;
  int R, C, bx, by, b;
  if (bid < 8192) {  // X: per batch 64 x 4 tiles, 32 batches
    src = X; dst = XT; R = 2048; C = 128;
    b = bid >> 8;
    int r = bid & 255;
    bx = r & 63; by = r >> 6;
  } else if (bid < 8192 + 32) {  // W1: 128 x 256 -> 4 x 8 tiles
    src = W1; dst = W1T; R = 128; C = 256; b = 0;
    int r = bid - 8192;
    bx = r & 3; by = r >> 2;
  } else {  // W2: 256 x 256 -> 8 x 8 tiles
    src = W2; dst = W2T; R = 256; C = 256; b = 0;
    int r = bid - 8224;
    bx = r & 7; by = r >> 3;
  }
  src += (size_t)b * R * C;
  dst += (size_t)b * R * C;
  __shared__ float tile[32][33];
  int r0 = bx * 32, c0 = by * 32;
  int t = threadIdx.x;
  int r = t >> 3, c4 = (t & 7) << 2;
  float4 v = *(const float4*)(src + (size_t)(r0 + r) * C + c0 + c4);
  tile[r][c4 + 0] = v.x; tile[r][c4 + 1] = v.y; tile[r][c4 + 2] = v.z; tile[r][c4 + 3] = v.w;
  __syncthreads();
  ushort4 o;
  o.x = f2bf(tile[c4 + 0][r]); o.y = f2bf(tile[c4 + 1][r]);
  o.z = f2bf(tile[c4 + 2][r]); o.w = f2bf(tile[c4 + 3][r]);
  *(ushort4*)(dst + (size_t)(c0 + r) * R + r0 + c4) = o;
}

// Fused: T = A[b] (NNxNN f32) @ B[b] (BT given, NCOLS x NN bf16), then
// out = relu(LN(T @ W + bias)) with W^T given (256 x NCOLS bf16).
// MODE 0: write out^T (b,256,NN); MODE 1: per-block column partials -> gpart.
// 512 threads, 8 waves (2 wr x 4 wc). Main: BM=128, BN=NCOLS, BK=64,
// depth-2 f32->bf16 A prefetch, 1 barrier/K-step.
// A loads are flat lane-contiguous: load j reads float4 (t + j*512) of the
// 128x16-float4 tile -> each instruction is a fully-packed 1 KB request.
#define AGG_STEP(KT, AREGC, AREGN, CUR)                                        \
  {                                                                            \
    const int kt_ = (KT);                                                      \
    if (kt_ < NKT - 2) { /* issue A loads for kt+2 */                          \
      const float* p_ = apb + (size_t)(kt_ + 2) * 64;                          \
      _Pragma("unroll") for (int j = 0; j < 4; ++j)                            \
          AREGN[j] = *(const float4*)(p_ + (size_t)j * 32 * NN);               \
    }                                                                          \
    if (kt_ < NKT - 1) {                                                       \
      _Pragma("unroll") for (int i = 0; i < NF; ++i) { /* B tile kt+1 */       \
        int jj = i * 512 + t;                                                  \
        int n_ = jj >> 3, s_ = jj & 7, sp_ = s_ ^ (n_ & 7);                    \
        gld_lds16(BTb + (size_t)n_ * NN + (size_t)(kt_ + 1) * 64 + sp_ * 8,    \
                  &Bs[(CUR) ^ 1][(i * 512 + wid * 64) * 8]);                   \
      }                                                                        \
      _Pragma("unroll") for (int j = 0; j < 4; ++j) { /* cvt A tile kt+1 */    \
        uint2 w_;                                                              \
        w_.x = pk2(AREGC[j].x, AREGC[j].y);                                    \
        w_.y = pk2(AREGC[j].z, AREGC[j].w);                                    \
        int row_ = arow + 32 * j;                                              \
        int sp_ = aslot ^ (row_ & 7);                                          \
        *(uint2*)&As[(CUR) ^ 1][(row_ * 8 + sp_) * 8 + ahalf * 4] = w_;        \
      }                                                                        \
    }                                                                          \
    _Pragma("unroll") for (int kh = 0; kh < 2; ++kh) {                         \
      bf16x8 af[4], bfr[NF];                                                   \
      _Pragma("unroll") for (int mi = 0; mi < 4; ++mi) {                       \
        int row = wr * 64 + mi * 16 + lr;                                      \
        int sp_ = (kh * 4 + q) ^ (row & 7);                                    \
        af[mi] = *(const bf16x8*)&As[CUR][(row * 8 + sp_) * 8];                \
      }                                                                        \
      _Pragma("unroll") for (int ni = 0; ni < NF; ++ni) {                      \
        int brow = wc * WN + ni * 16 + lr;                                     \
        int sp_ = (kh * 4 + q) ^ (brow & 7);                                   \
        bfr[ni] = *(const bf16x8*)&Bs[CUR][(brow * 8 + sp_) * 8];              \
      }                                                                        \
      _Pragma("unroll") for (int mi = 0; mi < 4; ++mi)                         \
        _Pragma("unroll") for (int ni = 0; ni < NF; ++ni)                      \
          acc[mi][ni] = __builtin_amdgcn_mfma_f32_16x16x32_bf16(               \
              af[mi], bfr[ni], acc[mi][ni], 0, 0, 0);                          \
    }                                                                          \
    __syncthreads();                                                           \
  }

template <int NCOLS, int MODE>
__global__ __launch_bounds__(512, NCOLS == 128 ? 4 : 2) void k_agg_fused(
    const float* __restrict__ A, const unsigned short* __restrict__ BT,
    const unsigned short* __restrict__ WT, const float* __restrict__ bias,
    const float* __restrict__ gamma, const float* __restrict__ beta,
    unsigned short* __restrict__ HTout, float* __restrict__ gpart) {
  constexpr int WN = NCOLS / 4;   // wave n-width in main loop
  constexpr int NF = NCOLS / 64;  // b-frag count / B-stage iters
  constexpr int NKT = NN / 64;    // 32 K-steps
  constexpr int FIN = NCOLS;      // K of the fused linear
  constexpr int NQT = FIN / 64;   // epilogue K-quarters
  constexpr int NMB = NN / 128;   // m-blocks per batch (16)

  __shared__ __align__(16) unsigned short As[2][128 * 64];
  __shared__ __align__(16) unsigned short Bs[2][NCOLS * 64];
  __shared__ float red[2][128][4];

  // XCD-aware swizzle: all blocks of one batch (sharing the BT panel) land
  // on one XCD, contiguous in dispatch order. Bijective (grid = 512).
  int L = blockIdx.x + gridDim.x * blockIdx.z;
  int xcd = L & 7, slot = L >> 3;
  int mb = slot % NMB;
  int b = xcd + 8 * (slot / NMB);
  int m0 = mb * 128;

  const float* Ab = A + (size_t)b * NN * NN;
  const unsigned short* BTb = BT + (size_t)b * (size_t)NCOLS * NN;
  int t = threadIdx.x, lane = t & 63, wid = t >> 6;
  int wr = wid >> 2, wc = wid & 3;
  int q = lane >> 4, lr = lane & 15;
  // A staging (flat-coalesced): load j covers row arow+32j, float4 col t&15
  int arow = t >> 4;            // base row [0,32)
  int aslot = (t >> 1) & 7;     // 8-bf16 slot within row
  int ahalf = t & 1;            // half-slot (4 bf16)
  const float* apb = Ab + (size_t)(m0 + arow) * NN + (t & 15) * 4;

  f32x4 acc[4][NF] = {};
  float4 aregA[4], aregB[4];

  // prologue: tile0 -> buf0; issue tile1 A loads
  {
#pragma unroll
    for (int j = 0; j < 4; ++j) aregA[j] = *(const float4*)(apb + (size_t)j * 32 * NN);
#pragma unroll
    for (int i = 0; i < NF; ++i) {
      int jj = i * 512 + t;
      int n = jj >> 3, s = jj & 7, sp = s ^ (n & 7);
      gld_lds16(BTb + (size_t)n * NN + sp * 8, &Bs[0][(i * 512 + wid * 64) * 8]);
    }
#pragma unroll
    for (int j = 0; j < 4; ++j) {
      uint2 w;
      w.x = pk2(aregA[j].x, aregA[j].y);
      w.y = pk2(aregA[j].z, aregA[j].w);
      int row_ = arow + 32 * j;
      int sp = aslot ^ (row_ & 7);
      *(uint2*)&As[0][(row_ * 8 + sp) * 8 + ahalf * 4] = w;
    }
#pragma unroll
    for (int j = 0; j < 4; ++j) aregB[j] = *(const float4*)(apb + 64 + (size_t)j * 32 * NN);
  }
  __syncthreads();

  for (int k2 = 0; k2 < NKT / 2; ++k2) {
    AGG_STEP(2 * k2, aregB, aregA, 0);
    AGG_STEP(2 * k2 + 1, aregA, aregB, 1);
  }

  // ---- epilogue: T(128 x FIN) -> bf16 Hs in LDS (swizzled) ----
  unsigned short* Hs = (NCOLS == 128) ? &As[0][0] : &Bs[0][0];
  unsigned short* Ws = (NCOLS == 128) ? &Bs[0][0] : &As[0][0];
#pragma unroll
  for (int mi = 0; mi < 4; ++mi) {
#pragma unroll
    for (int ni = 0; ni < NF; ++ni) {
#pragma unroll
      for (int j = 0; j < 4; ++j) {
        int row = wr * 64 + mi * 16 + q * 4 + j;
        int col = wc * WN + ni * 16 + lr;
        int sp = (col >> 3) ^ (row & 7);
        Hs[row * FIN + sp * 8 + (col & 7)] = f2bf(acc[mi][ni][j]);
      }
    }
  }

  // ---- linear: acc2 = Hs @ W, W^T staged in K-quarters of [256][64] ----
  f32x4 acc2[4][4] = {};
  for (int qt = 0; qt < NQT; ++qt) {
    __syncthreads();  // Hs visible / previous quarter's Ws reads done
#pragma unroll
    for (int i = 0; i < 4; ++i) {
      int jj = i * 512 + t;
      int h = jj >> 3, s = jj & 7, sp = s ^ (h & 7);
      gld_lds16(WT + (size_t)h * FIN + qt * 64 + sp * 8, Ws + (i * 512 + wid * 64) * 8);
    }
    __syncthreads();
#pragma unroll
    for (int kh = 0; kh < 2; ++kh) {
      bf16x8 hf[4], wf[4];
#pragma unroll
      for (int mi = 0; mi < 4; ++mi) {
        int row = wr * 64 + mi * 16 + lr;
        int slotk = qt * 8 + kh * 4 + q;
        int sp = slotk ^ (row & 7);
        hf[mi] = *(const bf16x8*)&Hs[row * FIN + sp * 8];
      }
#pragma unroll
      for (int ni = 0; ni < 4; ++ni) {
        int h = wc * 64 + ni * 16 + lr;
        int sp = (kh * 4 + q) ^ (h & 7);
        wf[ni] = *(const bf16x8*)&Ws[(h * 8 + sp) * 8];
      }
#pragma unroll
      for (int mi = 0; mi < 4; ++mi) {
#pragma unroll
        for (int ni = 0; ni < 4; ++ni)
          acc2[mi][ni] = __builtin_amdgcn_mfma_f32_16x16x32_bf16(hf[mi], wf[ni], acc2[mi][ni], 0, 0, 0);
      }
    }
  }

  // ---- bias + LayerNorm(256) + relu ----
  float bcol[4], gcol[4], zcol[4];
#pragma unroll
  for (int ni = 0; ni < 4; ++ni) {
    int col = wc * 64 + ni * 16 + lr;
    bcol[ni] = bias[col]; gcol[ni] = gamma[col]; zcol[ni] = beta[col];
  }
#pragma unroll
  for (int mi = 0; mi < 4; ++mi) {
#pragma unroll
    for (int j = 0; j < 4; ++j) {
      float s = 0.f, ss = 0.f;
#pragma unroll
      for (int ni = 0; ni < 4; ++ni) {
        float v = acc2[mi][ni][j] + bcol[ni];
        acc2[mi][ni][j] = v;
        s += v; ss += v * v;
      }
#pragma unroll
      for (int m = 1; m < 16; m <<= 1) { s += __shfl_xor(s, m); ss += __shfl_xor(ss, m); }
      if (lr == 0) {
        int rl = wr * 64 + mi * 16 + q * 4 + j;
        red[0][rl][wc] = s;
        red[1][rl][wc] = ss;
      }
    }
  }
  __syncthreads();
#pragma unroll
  for (int mi = 0; mi < 4; ++mi) {
#pragma unroll
    for (int j = 0; j < 4; ++j) {
      int rl = wr * 64 + mi * 16 + q * 4 + j;
      float s = red[0][rl][0] + red[0][rl][1] + red[0][rl][2] + red[0][rl][3];
      float ss = red[1][rl][0] + red[1][rl][1] + red[1][rl][2] + red[1][rl][3];
      float mean = s * (1.f / 256.f);
      float var = ss * (1.f / 256.f) - mean * mean;
      float inv = rsqrtf(var + 1e-5f);
#pragma unroll
      for (int ni = 0; ni < 4; ++ni) {
        float v = (acc2[mi][ni][j] - mean) * inv * gcol[ni] + zcol[ni];
        acc2[mi][ni][j] = v > 0.f ? v : 0.f;
      }
    }
  }
  if (MODE == 0) {
#pragma unroll
    for (int mi = 0; mi < 4; ++mi) {
#pragma unroll
      for (int ni = 0; ni < 4; ++ni) {
        int col = wc * 64 + ni * 16 + lr;
        int rowb = m0 + wr * 64 + mi * 16 + q * 4;
        ushort4 o;
        o.x = f2bf(acc2[mi][ni][0]); o.y = f2bf(acc2[mi][ni][1]);
        o.z = f2bf(acc2[mi][ni][2]); o.w = f2bf(acc2[mi][ni][3]);
        *(ushort4*)(HTout + ((size_t)b * 256 + col) * NN + rowb) = o;
      }
    }
  } else {
#pragma unroll
    for (int ni = 0; ni < 4; ++ni) {
      float cs = 0.f;
#pragma unroll
      for (int mi = 0; mi < 4; ++mi) {
#pragma unroll
        for (int j = 0; j < 4; ++j) cs += acc2[mi][ni][j];
      }
      cs += __shfl_xor(cs, 16);
      cs += __shfl_xor(cs, 32);
      if (q == 0) {
        int col = wc * 64 + ni * 16 + lr;
        gpart[(((size_t)b * NMB + mb) * 2 + wr) * 256 + col] = cs;
      }
    }
  }
}

__global__ void k_readout(const float* __restrict__ gpart, const float* __restrict__ Wa,
                          const float* __restrict__ ba, const float* __restrict__ Wl,
                          const float* __restrict__ bl, float* __restrict__ out) {
  __shared__ float gl[256];
  int b = blockIdx.x, t = threadIdx.x;  // 256 threads
  float s = 0.f;
#pragma unroll 4
  for (int p = 0; p < 32; ++p) s += gpart[((size_t)b * 32 + p) * 256 + t];
  gl[t] = s * (1.f / 2048.f);
  __syncthreads();
  if (t < 128) {
    int k = t & 63;
    const float* W = (t >= 64) ? Wl : Wa;
    const float* bb = (t >= 64) ? bl : ba;
    float a = 0.f;
    for (int h = 0; h < 256; ++h) a += gl[h] * W[h * 64 + k];
    a += bb[k];
    out[((t >= 64) ? 2048 : 0) + b * 64 + k] = a;
  }
}

extern "C" void kernel_launch(void* const* d_in, const int* in_sizes, int n_in,
                              void* d_out, int out_size, void* d_ws, size_t ws_size,
                              hipStream_t stream) {
  const float* A_hat = (const float*)d_in[0];
  const float* X   = (const float*)d_in[1];
  const float* W1  = (const float*)d_in[2];
  const float* b1  = (const float*)d_in[3];
  const float* g1  = (const float*)d_in[4];
  const float* be1 = (const float*)d_in[5];
  const float* W2  = (const float*)d_in[6];
  const float* b2  = (const float*)d_in[7];
  const float* g2  = (const float*)d_in[8];
  const float* be2 = (const float*)d_in[9];
  const float* Wa  = (const float*)d_in[10];
  const float* ba  = (const float*)d_in[11];
  const float* Wl  = (const float*)d_in[12];
  const float* bl  = (const float*)d_in[13];

  char* ws = (char*)d_ws;
  const size_t MB = 1024 * 1024;
  unsigned short* XT  = (unsigned short*)(ws);                         // 16 MiB (B,128,2048)
  unsigned short* H1T = (unsigned short*)(ws + 16 * MB);               // 32 MiB (B,256,2048)
  unsigned short* W1T = (unsigned short*)(ws + 48 * MB);               // 64 KB (256x128)
  unsigned short* W2T = (unsigned short*)(ws + 48 * MB + 256 * 1024);  // 128 KB (256x256)
  float* gpart        = (float*)(ws + 49 * MB);                        // 1 MiB (B,32,256)

  // prep: transposed bf16 copies (X + W1 + W2 in one launch)
  k_tr_all<<<dim3(8288), 256, 0, stream>>>(X, XT, W1, W1T, W2, W2T);
  // layer 1 fused: H1T = relu(LN(A@X @ W1 + b1))^T
  k_agg_fused<128, 0><<<dim3(16, 1, 32), 512, 0, stream>>>(
      A_hat, XT, W1T, b1, g1, be1, H1T, nullptr);
  // layer 2 fused: gpart partials of relu(LN(A@H1 @ W2 + b2))
  k_agg_fused<256, 1><<<dim3(16, 1, 32), 512, 0, stream>>>(
      A_hat, H1T, W2T, b2, g2, be2, nullptr, gpart);
  // readout
  k_readout<<<dim3(32), 256, 0, stream>>>(gpart, Wa, ba, Wl, bl, (float*)d_out);
}

// Round 7
// 322.799 us; speedup vs baseline: 1.0684x; 1.0684x over previous
//
#include <hip/hip_runtime.h>
#include <hip/hip_bf16.h>

#define NN 2048

typedef __attribute__((ext_vector_type(4))) float f32x4;
typedef __attribute__((ext_vector_type(8))) short bf16x8;

__device__ __forceinline__ unsigned short f2bf(float f) {
  __hip_bfloat16 h = __float2bfloat16(f);
  return __builtin_bit_cast(unsigned short, h);
}
__device__ __forceinline__ unsigned int pk2(float a, float b) {
  return (unsigned int)f2bf(a) | ((unsigned int)f2bf(b) << 16);
}
__device__ __forceinline__ void gld_lds16(const void* g, void* l) {
  __builtin_amdgcn_global_load_lds(
      (const __attribute__((address_space(1))) unsigned int*)g,
      (__attribute__((address_space(3))) unsigned int*)l, 16, 0, 0);
}

// Merged transpose+cvt: f32 (R x C) -> bf16 (C x R) for X (batched), W1, W2.
__global__ void k_tr_all(const float* __restrict__ X, unsigned short* __restrict__ XT,
                         const float* __restrict__ W1, unsigned short* __restrict__ W1T,
                         const float* __restrict__ W2, unsigned short* __restrict__ W2T) {
  int bid = blockIdx.x;
  const float* src;
  unsigned short* dst;
  int R, C, bx, by, b;
  if (bid < 8192) {  // X: per batch 64 x 4 tiles, 32 batches
    src = X; dst = XT; R = 2048; C = 128;
    b = bid >> 8;
    int r = bid & 255;
    bx = r & 63; by = r >> 6;
  } else if (bid < 8192 + 32) {  // W1: 128 x 256 -> 4 x 8 tiles
    src = W1; dst = W1T; R = 128; C = 256; b = 0;
    int r = bid - 8192;
    bx = r & 3; by = r >> 2;
  } else {  // W2: 256 x 256 -> 8 x 8 tiles
    src = W2; dst = W2T; R = 256; C = 256; b = 0;
    int r = bid - 8224;
    bx = r & 7; by = r >> 3;
  }
  src += (size_t)b * R * C;
  dst += (size_t)b * R * C;
  __shared__ float tile[32][33];
  int r0 = bx * 32, c0 = by * 32;
  int t = threadIdx.x;
  int r = t >> 3, c4 = (t & 7) << 2;
  float4 v = *(const float4*)(src + (size_t)(r0 + r) * C + c0 + c4);
  tile[r][c4 + 0] = v.x; tile[r][c4 + 1] = v.y; tile[r][c4 + 2] = v.z; tile[r][c4 + 3] = v.w;
  __syncthreads();
  ushort4 o;
  o.x = f2bf(tile[c4 + 0][r]); o.y = f2bf(tile[c4 + 1][r]);
  o.z = f2bf(tile[c4 + 2][r]); o.w = f2bf(tile[c4 + 3][r]);
  *(ushort4*)(dst + (size_t)(c0 + r) * R + r0 + c4) = o;
}

// Fused: T = A[b] (NNxNN f32) @ B[b] (BT given, NCOLS x NN bf16), then
// out = relu(LN(T @ W + bias)) with W^T given (256 x NCOLS bf16).
// MODE 0: write out^T (b,256,NN); MODE 1: per-block column partials -> gpart.
// 512 threads, 8 waves (2 wr x 4 wc). BM=128, BN=NCOLS, BK=64.
// Counted-vmcnt barrier (T4): B gld_lds for kt+1 issued FIRST, then A reg
// loads for kt+2; pre-barrier s_waitcnt vmcnt(4) leaves the 4 A loads in
// flight across the raw s_barrier (no full drain in the main loop).
#define AGG_STEP(KT, AREGC, AREGN, CUR, VMC)                                   \
  {                                                                            \
    const int kt_ = (KT);                                                      \
    if (kt_ < NKT - 1) { /* B tile kt+1 -> Bs[nxt]; issued first (oldest) */   \
      _Pragma("unroll") for (int i = 0; i < NF; ++i) {                         \
        int jj = i * 512 + t;                                                  \
        int n_ = jj >> 3, s_ = jj & 7, sp_ = s_ ^ (n_ & 7);                    \
        gld_lds16(BTb + (size_t)n_ * NN + (size_t)(kt_ + 1) * 64 + sp_ * 8,    \
                  &Bs[(CUR) ^ 1][(i * 512 + wid * 64) * 8]);                   \
      }                                                                        \
    }                                                                          \
    __builtin_amdgcn_sched_barrier(0); /* pin: B ops issue before A ops */     \
    if (kt_ < NKT - 2) { /* A loads for kt+2; stay in flight over barrier */   \
      const float* p_ = apb + (size_t)(kt_ + 2) * 64;                          \
      _Pragma("unroll") for (int j = 0; j < 4; ++j)                            \
          AREGN[j] = ((const float4*)p_)[j];                                   \
    }                                                                          \
    if (kt_ < NKT - 1) { /* cvt A(kt+1) regs (landed long ago) -> As[nxt] */   \
      _Pragma("unroll") for (int i = 0; i < 2; ++i) {                          \
        uint4 w_;                                                              \
        w_.x = pk2(AREGC[2 * i].x, AREGC[2 * i].y);                            \
        w_.y = pk2(AREGC[2 * i].z, AREGC[2 * i].w);                            \
        w_.z = pk2(AREGC[2 * i + 1].x, AREGC[2 * i + 1].y);                    \
        w_.w = pk2(AREGC[2 * i + 1].z, AREGC[2 * i + 1].w);                    \
        int s_ = ak * 2 + i, sp_ = s_ ^ (ar & 7);                              \
        *(uint4*)&As[(CUR) ^ 1][(ar * 8 + sp_) * 8] = w_;                      \
      }                                                                        \
    }                                                                          \
    _Pragma("unroll") for (int kh = 0; kh < 2; ++kh) {                         \
      bf16x8 af[4], bfr[NF];                                                   \
      _Pragma("unroll") for (int mi = 0; mi < 4; ++mi) {                       \
        int row = wr * 64 + mi * 16 + lr;                                      \
        int sp_ = (kh * 4 + q) ^ (row & 7);                                    \
        af[mi] = *(const bf16x8*)&As[CUR][(row * 8 + sp_) * 8];                \
      }                                                                        \
      _Pragma("unroll") for (int ni = 0; ni < NF; ++ni) {                      \
        int brow = wc * WN + ni * 16 + lr;                                     \
        int sp_ = (kh * 4 + q) ^ (brow & 7);                                   \
        bfr[ni] = *(const bf16x8*)&Bs[CUR][(brow * 8 + sp_) * 8];              \
      }                                                                        \
      _Pragma("unroll") for (int mi = 0; mi < 4; ++mi)                         \
        _Pragma("unroll") for (int ni = 0; ni < NF; ++ni)                      \
          acc[mi][ni] = __builtin_amdgcn_mfma_f32_16x16x32_bf16(               \
              af[mi], bfr[ni], acc[mi][ni], 0, 0, 0);                          \
    }                                                                          \
    asm volatile("s_waitcnt vmcnt(" #VMC ") lgkmcnt(0)" ::: "memory");         \
    __builtin_amdgcn_s_barrier();                                              \
  }

template <int NCOLS, int MODE>
__global__ __launch_bounds__(512, NCOLS == 128 ? 4 : 2) void k_agg_fused(
    const float* __restrict__ A, const unsigned short* __restrict__ BT,
    const unsigned short* __restrict__ WT, const float* __restrict__ bias,
    const float* __restrict__ gamma, const float* __restrict__ beta,
    unsigned short* __restrict__ HTout, float* __restrict__ gpart) {
  constexpr int WN = NCOLS / 4;   // wave n-width in main loop
  constexpr int NF = NCOLS / 64;  // b-frag count / B-stage iters
  constexpr int NKT = NN / 64;    // 32 K-steps
  constexpr int FIN = NCOLS;      // K of the fused linear
  constexpr int NQT = FIN / 64;   // epilogue K-quarters
  constexpr int NMB = NN / 128;   // m-blocks per batch (16)

  __shared__ __align__(16) unsigned short As[2][128 * 64];
  __shared__ __align__(16) unsigned short Bs[2][NCOLS * 64];
  __shared__ float red[2][128][4];

  // XCD-aware swizzle: all blocks of one batch (sharing the BT panel) land
  // on one XCD, contiguous in dispatch order. Bijective (grid = 512).
  int L = blockIdx.x + gridDim.x * blockIdx.z;
  int xcd = L & 7, slot = L >> 3;
  int mb = slot % NMB;
  int b = xcd + 8 * (slot / NMB);
  int m0 = mb * 128;

  const float* Ab = A + (size_t)b * NN * NN;
  const unsigned short* BTb = BT + (size_t)b * (size_t)NCOLS * NN;
  int t = threadIdx.x, lane = t & 63, wid = t >> 6;
  int wr = wid >> 2, wc = wid & 3;
  int q = lane >> 4, lr = lane & 15;
  int ar = t >> 2, ak = t & 3;  // A staging: row, 16-f32 chunk
  const float* apb = Ab + (size_t)(m0 + ar) * NN + ak * 16;

  f32x4 acc[4][NF] = {};
  float4 aregA[4], aregB[4];

  // prologue: A(0) loads, B(0) gld_lds, cvt A(0)->As[0], A(1) loads,
  // counted wait (B(0) done, A(1) in flight), barrier.
  {
#pragma unroll
    for (int j = 0; j < 4; ++j) aregA[j] = ((const float4*)apb)[j];
#pragma unroll
    for (int i = 0; i < NF; ++i) {
      int jj = i * 512 + t;
      int n = jj >> 3, s = jj & 7, sp = s ^ (n & 7);
      gld_lds16(BTb + (size_t)n * NN + sp * 8, &Bs[0][(i * 512 + wid * 64) * 8]);
    }
#pragma unroll
    for (int i = 0; i < 2; ++i) {
      uint4 w;
      w.x = pk2(aregA[2 * i].x, aregA[2 * i].y);
      w.y = pk2(aregA[2 * i].z, aregA[2 * i].w);
      w.z = pk2(aregA[2 * i + 1].x, aregA[2 * i + 1].y);
      w.w = pk2(aregA[2 * i + 1].z, aregA[2 * i + 1].w);
      int s = ak * 2 + i, sp = s ^ (ar & 7);
      *(uint4*)&As[0][(ar * 8 + sp) * 8] = w;
    }
    __builtin_amdgcn_sched_barrier(0);
#pragma unroll
    for (int j = 0; j < 4; ++j) aregB[j] = ((const float4*)(apb + 64))[j];
    asm volatile("s_waitcnt vmcnt(4) lgkmcnt(0)" ::: "memory");
    __builtin_amdgcn_s_barrier();
  }

  for (int k2 = 0; k2 < NKT / 2 - 1; ++k2) {
    AGG_STEP(2 * k2, aregB, aregA, 0, 4);
    AGG_STEP(2 * k2 + 1, aregA, aregB, 1, 4);
  }
  AGG_STEP(NKT - 2, aregB, aregA, 0, 0);
  AGG_STEP(NKT - 1, aregA, aregB, 1, 0);

  // ---- epilogue: T(128 x FIN) -> bf16 Hs in LDS (swizzled) ----
  unsigned short* Hs = (NCOLS == 128) ? &As[0][0] : &Bs[0][0];
  unsigned short* Ws = (NCOLS == 128) ? &Bs[0][0] : &As[0][0];
#pragma unroll
  for (int mi = 0; mi < 4; ++mi) {
#pragma unroll
    for (int ni = 0; ni < NF; ++ni) {
#pragma unroll
      for (int j = 0; j < 4; ++j) {
        int row = wr * 64 + mi * 16 + q * 4 + j;
        int col = wc * WN + ni * 16 + lr;
        int sp = (col >> 3) ^ (row & 7);
        Hs[row * FIN + sp * 8 + (col & 7)] = f2bf(acc[mi][ni][j]);
      }
    }
  }

  // ---- linear: acc2 = Hs @ W, W^T staged in K-quarters of [256][64] ----
  f32x4 acc2[4][4] = {};
  for (int qt = 0; qt < NQT; ++qt) {
    __syncthreads();  // Hs visible / previous quarter's Ws reads done
#pragma unroll
    for (int i = 0; i < 4; ++i) {
      int jj = i * 512 + t;
      int h = jj >> 3, s = jj & 7, sp = s ^ (h & 7);
      gld_lds16(WT + (size_t)h * FIN + qt * 64 + sp * 8, Ws + (i * 512 + wid * 64) * 8);
    }
    __syncthreads();
#pragma unroll
    for (int kh = 0; kh < 2; ++kh) {
      bf16x8 hf[4], wf[4];
#pragma unroll
      for (int mi = 0; mi < 4; ++mi) {
        int row = wr * 64 + mi * 16 + lr;
        int slotk = qt * 8 + kh * 4 + q;
        int sp = slotk ^ (row & 7);
        hf[mi] = *(const bf16x8*)&Hs[row * FIN + sp * 8];
      }
#pragma unroll
      for (int ni = 0; ni < 4; ++ni) {
        int h = wc * 64 + ni * 16 + lr;
        int sp = (kh * 4 + q) ^ (h & 7);
        wf[ni] = *(const bf16x8*)&Ws[(h * 8 + sp) * 8];
      }
#pragma unroll
      for (int mi = 0; mi < 4; ++mi) {
#pragma unroll
        for (int ni = 0; ni < 4; ++ni)
          acc2[mi][ni] = __builtin_amdgcn_mfma_f32_16x16x32_bf16(hf[mi], wf[ni], acc2[mi][ni], 0, 0, 0);
      }
    }
  }

  // ---- bias + LayerNorm(256) + relu ----
  float bcol[4], gcol[4], zcol[4];
#pragma unroll
  for (int ni = 0; ni < 4; ++ni) {
    int col = wc * 64 + ni * 16 + lr;
    bcol[ni] = bias[col]; gcol[ni] = gamma[col]; zcol[ni] = beta[col];
  }
#pragma unroll
  for (int mi = 0; mi < 4; ++mi) {
#pragma unroll
    for (int j = 0; j < 4; ++j) {
      float s = 0.f, ss = 0.f;
#pragma unroll
      for (int ni = 0; ni < 4; ++ni) {
        float v = acc2[mi][ni][j] + bcol[ni];
        acc2[mi][ni][j] = v;
        s += v; ss += v * v;
      }
#pragma unroll
      for (int m = 1; m < 16; m <<= 1) { s += __shfl_xor(s, m); ss += __shfl_xor(ss, m); }
      if (lr == 0) {
        int rl = wr * 64 + mi * 16 + q * 4 + j;
        red[0][rl][wc] = s;
        red[1][rl][wc] = ss;
      }
    }
  }
  __syncthreads();
#pragma unroll
  for (int mi = 0; mi < 4; ++mi) {
#pragma unroll
    for (int j = 0; j < 4; ++j) {
      int rl = wr * 64 + mi * 16 + q * 4 + j;
      float s = red[0][rl][0] + red[0][rl][1] + red[0][rl][2] + red[0][rl][3];
      float ss = red[1][rl][0] + red[1][rl][1] + red[1][rl][2] + red[1][rl][3];
      float mean = s * (1.f / 256.f);
      float var = ss * (1.f / 256.f) - mean * mean;
      float inv = rsqrtf(var + 1e-5f);
#pragma unroll
      for (int ni = 0; ni < 4; ++ni) {
        float v = (acc2[mi][ni][j] - mean) * inv * gcol[ni] + zcol[ni];
        acc2[mi][ni][j] = v > 0.f ? v : 0.f;
      }
    }
  }
  if (MODE == 0) {
#pragma unroll
    for (int mi = 0; mi < 4; ++mi) {
#pragma unroll
      for (int ni = 0; ni < 4; ++ni) {
        int col = wc * 64 + ni * 16 + lr;
        int rowb = m0 + wr * 64 + mi * 16 + q * 4;
        ushort4 o;
        o.x = f2bf(acc2[mi][ni][0]); o.y = f2bf(acc2[mi][ni][1]);
        o.z = f2bf(acc2[mi][ni][2]); o.w = f2bf(acc2[mi][ni][3]);
        *(ushort4*)(HTout + ((size_t)b * 256 + col) * NN + rowb) = o;
      }
    }
  } else {
#pragma unroll
    for (int ni = 0; ni < 4; ++ni) {
      float cs = 0.f;
#pragma unroll
      for (int mi = 0; mi < 4; ++mi) {
#pragma unroll
        for (int j = 0; j < 4; ++j) cs += acc2[mi][ni][j];
      }
      cs += __shfl_xor(cs, 16);
      cs += __shfl_xor(cs, 32);
      if (q == 0) {
        int col = wc * 64 + ni * 16 + lr;
        gpart[(((size_t)b * NMB + mb) * 2 + wr) * 256 + col] = cs;
      }
    }
  }
}

__global__ void k_readout(const float* __restrict__ gpart, const float* __restrict__ Wa,
                          const float* __restrict__ ba, const float* __restrict__ Wl,
                          const float* __restrict__ bl, float* __restrict__ out) {
  __shared__ float gl[256];
  int b = blockIdx.x, t = threadIdx.x;  // 256 threads
  float s = 0.f;
#pragma unroll 4
  for (int p = 0; p < 32; ++p) s += gpart[((size_t)b * 32 + p) * 256 + t];
  gl[t] = s * (1.f / 2048.f);
  __syncthreads();
  if (t < 128) {
    int k = t & 63;
    const float* W = (t >= 64) ? Wl : Wa;
    const float* bb = (t >= 64) ? bl : ba;
    float a = 0.f;
    for (int h = 0; h < 256; ++h) a += gl[h] * W[h * 64 + k];
    a += bb[k];
    out[((t >= 64) ? 2048 : 0) + b * 64 + k] = a;
  }
}

extern "C" void kernel_launch(void* const* d_in, const int* in_sizes, int n_in,
                              void* d_out, int out_size, void* d_ws, size_t ws_size,
                              hipStream_t stream) {
  const float* A_hat = (const float*)d_in[0];
  const float* X   = (const float*)d_in[1];
  const float* W1  = (const float*)d_in[2];
  const float* b1  = (const float*)d_in[3];
  const float* g1  = (const float*)d_in[4];
  const float* be1 = (const float*)d_in[5];
  const float* W2  = (const float*)d_in[6];
  const float* b2  = (const float*)d_in[7];
  const float* g2  = (const float*)d_in[8];
  const float* be2 = (const float*)d_in[9];
  const float* Wa  = (const float*)d_in[10];
  const float* ba  = (const float*)d_in[11];
  const float* Wl  = (const float*)d_in[12];
  const float* bl  = (const float*)d_in[13];

  char* ws = (char*)d_ws;
  const size_t MB = 1024 * 1024;
  unsigned short* XT  = (unsigned short*)(ws);                         // 16 MiB (B,128,2048)
  unsigned short* H1T = (unsigned short*)(ws + 16 * MB);               // 32 MiB (B,256,2048)
  unsigned short* W1T = (unsigned short*)(ws + 48 * MB);               // 64 KB (256x128)
  unsigned short* W2T = (unsigned short*)(ws + 48 * MB + 256 * 1024);  // 128 KB (256x256)
  float* gpart        = (float*)(ws + 49 * MB);                        // 1 MiB (B,32,256)

  // prep: transposed bf16 copies (X + W1 + W2 in one launch)
  k_tr_all<<<dim3(8288), 256, 0, stream>>>(X, XT, W1, W1T, W2, W2T);
  // layer 1 fused: H1T = relu(LN(A@X @ W1 + b1))^T
  k_agg_fused<128, 0><<<dim3(16, 1, 32), 512, 0, stream>>>(
      A_hat, XT, W1T, b1, g1, be1, H1T, nullptr);
  // layer 2 fused: gpart partials of relu(LN(A@H1 @ W2 + b2))
  k_agg_fused<256, 1><<<dim3(16, 1, 32), 512, 0, stream>>>(
      A_hat, H1T, W2T, b2, g2, be2, nullptr, gpart);
  // readout
  k_readout<<<dim3(32), 256, 0, stream>>>(gpart, Wa, ba, Wl, bl, (float*)d_out);
}